// Round 2
// baseline (544.912 us; speedup 1.0000x reference)
//
#include <hip/hip_runtime.h>

// ChunkedSelfAttention: B=2, T=4096, H=16, Dh=Dv=128, CHUNK=2048, causal per chunk,
// RoPE(base 10000) applied to q,k. No 1/sqrt(d) scale. fp32 in/out, fp16 MFMA inside
// (fp16 mantissa 11 bits vs bf16 8 -> 8x lower score error; same MFMA rate).

#define T_TOT  4096
#define HH     16
#define DH     128
#define CHUNKL 2048
#define QT     128          // q rows per block
#define KTILE  64           // keys per LDS tile
#define THREADS 256
#define NEGV   1e30f
#define L2E    1.44269504088896f

typedef _Float16 f16;
typedef __attribute__((ext_vector_type(8))) _Float16 f16x8;
typedef __attribute__((ext_vector_type(4))) _Float16 f16x4;
typedef __attribute__((ext_vector_type(4))) float    f32x4;

__device__ __forceinline__ f32x4 mfma16(f16x8 a, f16x8 b, f32x4 c) {
    return __builtin_amdgcn_mfma_f32_16x16x32_f16(a, b, c, 0, 0, 0);
}

// cos at tab[t*64+d], sin at tab[T*64 + t*64+d], d in [0,64)
__global__ void rope_table_kernel(float* __restrict__ tab, const int* __restrict__ startp) {
    int gid = blockIdx.x * blockDim.x + threadIdx.x;   // [0, 4096*64)
    int t = gid >> 6, d = gid & 63;
    float pos  = (float)(t + *startp);
    float invf = expf((float)d * (-9.210340371976184f / 64.0f));
    float s, c;
    sincosf(pos * invf, &s, &c);
    tab[gid] = c;
    tab[T_TOT * 64 + gid] = s;
}

template<bool USE_TABLE>
__global__ __launch_bounds__(THREADS, 2)
void attn_kernel(const float* __restrict__ Q, const float* __restrict__ K,
                 const float* __restrict__ V, const int* __restrict__ startp,
                 const float* __restrict__ tab, float* __restrict__ O)
{
    // K tile: [key][d] f16, XOR-swizzled (d ^ ((key&7)<<3)) -> conflict-free b128 reads
    __shared__ f16 Kl[KTILE * DH];
    // V tile transposed: [d][key] f16, swizzled (key ^ ((d&7)<<3))
    __shared__ f16 VTl[DH * KTILE];
    // P round-trip, per wave: 32 rows x 64 keys, stride 72 (pad) f16
    __shared__ f16 Pl[4][32 * 72];

    const int bid = blockIdx.x;
    const int qt  = 15 - (bid & 15);         // longest blocks first
    const int bnh = bid >> 4;
    const int h = bnh & 15, n = (bnh >> 4) & 1, b = bnh >> 5;

    const int tid  = threadIdx.x;
    const int w    = tid >> 6;
    const int lane = tid & 63;
    const int g    = lane >> 4, m = lane & 15;

    const int q0 = qt * QT;                  // chunk-local q base of this block
    const size_t bh = (size_t)b * T_TOT * (HH * DH) + (size_t)h * DH; // + t*2048 + d

    const int start = USE_TABLE ? 0 : *startp;

    // ---------------- Q fragments (RoPE'd, f16), accumulators ----------------
    f16x8  qf[2][4];
    float  mrun[2][4], lrun[2][4];
    f32x4  o[2][8];
    const f32x4 ZERO4 = {0.f, 0.f, 0.f, 0.f};

#pragma unroll
    for (int rs = 0; rs < 2; ++rs) {
#pragma unroll
        for (int r = 0; r < 4; ++r) { mrun[rs][r] = -NEGV; lrun[rs][r] = 0.f; }
#pragma unroll
        for (int dt = 0; dt < 8; ++dt) o[rs][dt] = ZERO4;

        const int tg = n * CHUNKL + q0 + w * 32 + rs * 16 + m;   // global t of this lane's A-row
        const float* qp = Q + bh + (size_t)tg * (HH * DH);
#pragma unroll
        for (int kc = 0; kc < 4; ++kc) {
            const int dbase = kc * 32 + g * 8;
            const int dlo   = dbase & 63;
            f32x4 xa0 = *(const f32x4*)(qp + dbase);
            f32x4 xa1 = *(const f32x4*)(qp + dbase + 4);
            f32x4 xb0 = *(const f32x4*)(qp + (dbase ^ 64));
            f32x4 xb1 = *(const f32x4*)(qp + (dbase ^ 64) + 4);
            float cc[8], ss[8];
            if (USE_TABLE) {
                *(f32x4*)&cc[0] = *(const f32x4*)(tab + tg * 64 + dlo);
                *(f32x4*)&cc[4] = *(const f32x4*)(tab + tg * 64 + dlo + 4);
                *(f32x4*)&ss[0] = *(const f32x4*)(tab + T_TOT * 64 + tg * 64 + dlo);
                *(f32x4*)&ss[4] = *(const f32x4*)(tab + T_TOT * 64 + tg * 64 + dlo + 4);
            } else {
#pragma unroll
                for (int j = 0; j < 8; ++j) {
                    float invf = expf((float)(dlo + j) * (-9.210340371976184f / 64.0f));
                    sincosf((float)(tg + start) * invf, &ss[j], &cc[j]);
                }
            }
            const float sgn = (dbase < 64) ? -1.f : 1.f;
            float xa[8] = {xa0[0],xa0[1],xa0[2],xa0[3],xa1[0],xa1[1],xa1[2],xa1[3]};
            float xb[8] = {xb0[0],xb0[1],xb0[2],xb0[3],xb1[0],xb1[1],xb1[2],xb1[3]};
            f16x8 f;
#pragma unroll
            for (int j = 0; j < 8; ++j) f[j] = (f16)(xa[j] * cc[j] + sgn * xb[j] * ss[j]);
            qf[rs][kc] = f;
        }
    }

    // ---------------- main K/V-tile loop ----------------
    const int nkt = 2 * qt + 2;
    for (int kt = 0; kt < nkt; ++kt) {
        __syncthreads();

        // ---- stage K tile with RoPE, swizzled ----
#pragma unroll
        for (int it = 0; it < 4; ++it) {
            const int tau = tid + THREADS * it;          // [0,1024)
            const int row = tau >> 4;                    // [0,64)
            const int d0  = (tau & 15) << 2;             // [0,64) step 4
            const int tg  = n * CHUNKL + kt * KTILE + row;
            const float* kp = K + bh + (size_t)tg * (HH * DH);
            f32x4 xa = *(const f32x4*)(kp + d0);
            f32x4 xb = *(const f32x4*)(kp + d0 + 64);
            f32x4 cc, ss;
            if (USE_TABLE) {
                cc = *(const f32x4*)(tab + tg * 64 + d0);
                ss = *(const f32x4*)(tab + T_TOT * 64 + tg * 64 + d0);
            } else {
#pragma unroll
                for (int j = 0; j < 4; ++j) {
                    float invf = expf((float)(d0 + j) * (-9.210340371976184f / 64.0f));
                    float sv, cv;
                    sincosf((float)(tg + start) * invf, &sv, &cv);
                    cc[j] = cv; ss[j] = sv;
                }
            }
            f16x4 oA, oB;
#pragma unroll
            for (int j = 0; j < 4; ++j) {
                oA[j] = (f16)(xa[j] * cc[j] - xb[j] * ss[j]);
                oB[j] = (f16)(xb[j] * cc[j] + xa[j] * ss[j]);
            }
            const int sw = (row & 7) << 3;
            *(f16x4*)&Kl[row * DH + (d0 ^ sw)]        = oA;
            *(f16x4*)&Kl[row * DH + ((d0 + 64) ^ sw)] = oB;
        }

        // ---- stage V tile transposed, swizzled ----
#pragma unroll
        for (int it = 0; it < 8; ++it) {
            const int tau = tid + THREADS * it;          // [0,2048)
            const int key = tau & 63;
            const int d0  = (tau >> 6) << 2;             // [0,128) step 4
            const int tg  = n * CHUNKL + kt * KTILE + key;
            f32x4 x = *(const f32x4*)(V + bh + (size_t)tg * (HH * DH) + d0);
#pragma unroll
            for (int j = 0; j < 4; ++j) {
                const int d = d0 + j;
                VTl[d * KTILE + (key ^ ((d & 7) << 3))] = (f16)x[j];
            }
        }
        __syncthreads();

        // waves whose rows are entirely below this key tile skip compute
        const bool active = (kt * KTILE) < (q0 + w * 32 + 32);
        if (active) {
            // ---- QK^T : S[32 q][64 k] per wave, two 16-row sets ----
            f32x4 sa[2][4];
#pragma unroll
            for (int rs = 0; rs < 2; ++rs)
#pragma unroll
                for (int nt = 0; nt < 4; ++nt) sa[rs][nt] = ZERO4;

#pragma unroll
            for (int nt = 0; nt < 4; ++nt) {
                const int key = nt * 16 + m;
                const int swk = (key & 7) << 3;
#pragma unroll
                for (int kc = 0; kc < 4; ++kc) {
                    f16x8 bf = *(const f16x8*)&Kl[key * DH + ((kc * 32 + g * 8) ^ swk)];
                    sa[0][nt] = mfma16(qf[0][kc], bf, sa[0][nt]);
                    sa[1][nt] = mfma16(qf[1][kc], bf, sa[1][nt]);
                }
            }

            // ---- online softmax per row set ----
            const bool domask = (kt >= 2 * qt);
#pragma unroll
            for (int rs = 0; rs < 2; ++rs) {
                if (domask) {
#pragma unroll
                    for (int nt = 0; nt < 4; ++nt) {
                        const int key = kt * KTILE + nt * 16 + m;
#pragma unroll
                        for (int r = 0; r < 4; ++r) {
                            const int qr = q0 + w * 32 + rs * 16 + 4 * g + r;
                            if (key > qr) sa[rs][nt][r] = -NEGV;
                        }
                    }
                }
                float mx[4];
#pragma unroll
                for (int r = 0; r < 4; ++r)
                    mx[r] = fmaxf(fmaxf(sa[rs][0][r], sa[rs][1][r]),
                                  fmaxf(sa[rs][2][r], sa[rs][3][r]));
#pragma unroll
                for (int off = 1; off < 16; off <<= 1)
#pragma unroll
                    for (int r = 0; r < 4; ++r)
                        mx[r] = fmaxf(mx[r], __shfl_xor(mx[r], off));

                float al[4], ps[4];
#pragma unroll
                for (int r = 0; r < 4; ++r) {
                    const float mn = fmaxf(mrun[rs][r], mx[r]);
                    al[r] = exp2f((mrun[rs][r] - mn) * L2E);
                    mrun[rs][r] = mn;
                    ps[r] = 0.f;
                }
#pragma unroll
                for (int nt = 0; nt < 4; ++nt)
#pragma unroll
                    for (int r = 0; r < 4; ++r) {
                        const float p = exp2f((sa[rs][nt][r] - mrun[rs][r]) * L2E);
                        sa[rs][nt][r] = p;
                        ps[r] += p;
                    }
#pragma unroll
                for (int off = 1; off < 16; off <<= 1)
#pragma unroll
                    for (int r = 0; r < 4; ++r)
                        ps[r] += __shfl_xor(ps[r], off);
#pragma unroll
                for (int r = 0; r < 4; ++r)
                    lrun[rs][r] = lrun[rs][r] * al[r] + ps[r];
#pragma unroll
                for (int dt = 0; dt < 8; ++dt)
#pragma unroll
                    for (int r = 0; r < 4; ++r)
                        o[rs][dt][r] *= al[r];
                // P -> LDS (f16), C-layout scatter
#pragma unroll
                for (int nt = 0; nt < 4; ++nt)
#pragma unroll
                    for (int r = 0; r < 4; ++r)
                        Pl[w][(rs * 16 + 4 * g + r) * 72 + nt * 16 + m] = (f16)sa[rs][nt][r];
            }

            // ---- P A-fragments ----
            f16x8 pa[2][2];
#pragma unroll
            for (int rs = 0; rs < 2; ++rs)
#pragma unroll
                for (int kc = 0; kc < 2; ++kc)
                    pa[rs][kc] = *(const f16x8*)&Pl[w][(rs * 16 + m) * 72 + kc * 32 + g * 8];

            // ---- PV ----
#pragma unroll
            for (int dt = 0; dt < 8; ++dt) {
                const int d   = dt * 16 + m;
                const int swv = (d & 7) << 3;
#pragma unroll
                for (int kc = 0; kc < 2; ++kc) {
                    f16x8 vf = *(const f16x8*)&VTl[d * KTILE + ((kc * 32 + g * 8) ^ swv)];
                    o[0][dt] = mfma16(pa[0][kc], vf, o[0][dt]);
                    o[1][dt] = mfma16(pa[1][kc], vf, o[1][dt]);
                }
            }
        }
    }

    // ---------------- epilogue: normalize + store fp32 ----------------
#pragma unroll
    for (int rs = 0; rs < 2; ++rs) {
#pragma unroll
        for (int r = 0; r < 4; ++r) {
            const float inv = 1.0f / lrun[rs][r];
            const int tg = n * CHUNKL + q0 + w * 32 + rs * 16 + 4 * g + r;
            float* op = O + bh + (size_t)tg * (HH * DH);
#pragma unroll
            for (int dt = 0; dt < 8; ++dt)
                op[dt * 16 + m] = o[rs][dt][r] * inv;
        }
    }
}

extern "C" void kernel_launch(void* const* d_in, const int* in_sizes, int n_in,
                              void* d_out, int out_size, void* d_ws, size_t ws_size,
                              hipStream_t stream) {
    const float* q = (const float*)d_in[0];
    const float* k = (const float*)d_in[1];
    const float* v = (const float*)d_in[2];
    const int* start = (const int*)d_in[3];
    float* out = (float*)d_out;

    const size_t tab_bytes = (size_t)2 * T_TOT * 64 * sizeof(float); // 2 MB
    const int nblocks = 64 * 16;  // (b,n,h) x q-tiles

    if (ws_size >= tab_bytes) {
        float* tab = (float*)d_ws;
        rope_table_kernel<<<(T_TOT * 64) / THREADS, THREADS, 0, stream>>>(tab, start);
        attn_kernel<true><<<nblocks, THREADS, 0, stream>>>(q, k, v, start, tab, out);
    } else {
        attn_kernel<false><<<nblocks, THREADS, 0, stream>>>(q, k, v, start, nullptr, out);
    }
}

// Round 3
// 365.406 us; speedup vs baseline: 1.4913x; 1.4913x over previous
//
#include <hip/hip_runtime.h>

// ChunkedSelfAttention: B=2, T=4096, H=16, Dh=Dv=128, CHUNK=2048, causal per chunk,
// RoPE(base 10000) on q,k. No 1/sqrt(d) scale. fp32 in/out, fp16 MFMA inside.
// R3: precompute RoPE'd K (fp16, tile-swizzled) and transposed V (fp16, tile-swizzled)
// into d_ws; hot loop stages via global_load_lds (16B) with zero VALU.

#define T_TOT  4096
#define HH     16
#define DH     128
#define CHUNKL 2048
#define QT     128          // q rows per block
#define KTILE  64           // keys per LDS tile
#define THREADS 256
#define NEGV   1e30f
#define L2E    1.44269504088896f

typedef _Float16 f16;
typedef __attribute__((ext_vector_type(8))) _Float16 f16x8;
typedef __attribute__((ext_vector_type(4))) _Float16 f16x4;
typedef __attribute__((ext_vector_type(4))) float    f32x4;

#define AS_G(p) ((const __attribute__((address_space(1))) void*)(p))
#define AS_L(p) ((__attribute__((address_space(3))) void*)(p))

__device__ __forceinline__ f32x4 mfma16(f16x8 a, f16x8 b, f32x4 c) {
    return __builtin_amdgcn_mfma_f32_16x16x32_f16(a, b, c, 0, 0, 0);
}

// cos at tab[t*64+d], sin at tab[T*64 + t*64+d], d in [0,64)
__global__ void rope_table_kernel(float* __restrict__ tab, const int* __restrict__ startp) {
    int gid = blockIdx.x * blockDim.x + threadIdx.x;   // [0, 4096*64)
    int t = gid >> 6, d = gid & 63;
    float pos  = (float)(t + *startp);
    float invf = expf((float)d * (-9.210340371976184f / 64.0f));
    float s, c;
    sincosf(pos * invf, &s, &c);
    tab[gid] = c;
    tab[T_TOT * 64 + gid] = s;
}

// K[b][t][h][0:128] fp32 -> RoPE -> fp16, stored per (b,n,h,kt) 64x128 tile,
// element (key,d) at tile + key*128 + (d ^ ((key&7)<<3)).
__global__ void prep_k_kernel(const float* __restrict__ K, const float* __restrict__ tab,
                              f16* __restrict__ Kws) {
    int gid = blockIdx.x * blockDim.x + threadIdx.x;   // [0, 2*4096*16*16)
    int q4 = gid & 15, r = gid >> 4;                   // r = global row id
    int h = r & 15, t = (r >> 4) & 4095, b = r >> 16;
    int d0 = q4 << 2;                                  // [0,64) step 4
    const float* kp = K + (size_t)r * DH;
    f32x4 xa = *(const f32x4*)(kp + d0);
    f32x4 xb = *(const f32x4*)(kp + d0 + 64);
    f32x4 cc = *(const f32x4*)(tab + t * 64 + d0);
    f32x4 ss = *(const f32x4*)(tab + T_TOT * 64 + t * 64 + d0);
    f16x4 oA, oB;
#pragma unroll
    for (int j = 0; j < 4; ++j) {
        oA[j] = (f16)(xa[j] * cc[j] - xb[j] * ss[j]);
        oB[j] = (f16)(xb[j] * cc[j] + xa[j] * ss[j]);
    }
    int n = t >> 11, rem = t & 2047, kt = rem >> 6, key = rem & 63;
    size_t tb = ((size_t)((((b * 2 + n) * 16 + h) * 32) + kt)) * 8192;
    int sw = (key & 7) << 3;
    *(f16x4*)&Kws[tb + key * DH + (d0 ^ sw)]        = oA;
    *(f16x4*)&Kws[tb + key * DH + ((d0 + 64) ^ sw)] = oB;
}

// V[b][t][h][0:128] fp32 -> fp16 transposed per tile: element (d,key) at
// tile + d*64 + (key ^ ((d&7)<<3)).
__global__ void prep_v_kernel(const float* __restrict__ V, f16* __restrict__ VTws) {
    int gid = blockIdx.x * blockDim.x + threadIdx.x;   // [0, 2*4096*16*32)
    int q4 = gid & 31, r = gid >> 5;
    int h = r & 15, t = (r >> 4) & 4095, b = r >> 16;
    int d0 = q4 << 2;                                  // [0,128) step 4
    f32x4 x = *(const f32x4*)(V + (size_t)r * DH + d0);
    int n = t >> 11, rem = t & 2047, kt = rem >> 6, key = rem & 63;
    size_t tb = ((size_t)((((b * 2 + n) * 16 + h) * 32) + kt)) * 8192;
#pragma unroll
    for (int j = 0; j < 4; ++j) {
        int d = d0 + j;
        VTws[tb + d * KTILE + (key ^ ((d & 7) << 3))] = (f16)x[j];
    }
}

// ---------------------------------------------------------------------------
// Fast attention: K/V pre-staged fp16 swizzled tiles in ws, global_load_lds staging.
__global__ __launch_bounds__(THREADS, 2)
void attn_fast_kernel(const float* __restrict__ Q, const f16* __restrict__ Kws,
                      const f16* __restrict__ VTws, const float* __restrict__ tab,
                      float* __restrict__ O)
{
    __shared__ f16 Kl[KTILE * DH];        // swizzled [key][d]
    __shared__ f16 VTl[DH * KTILE];       // swizzled [d][key]
    __shared__ f16 Pl[4][32 * 72];        // per-wave P roundtrip

    // XCD-chunked swizzle: all 16 q-blocks of one (b,n,h) on one XCD.
    const int bid = blockIdx.x;
    const int sb  = (bid & 7) * 128 + (bid >> 3);
    const int qt  = 15 - (sb & 15);       // longest blocks first within XCD
    const int bnh = sb >> 4;
    const int h = bnh & 15, n = (bnh >> 4) & 1, b = bnh >> 5;

    const int tid  = threadIdx.x;
    const int w    = tid >> 6;
    const int lane = tid & 63;
    const int g    = lane >> 4, m = lane & 15;

    const int q0 = qt * QT;
    const size_t bh = (size_t)b * T_TOT * (HH * DH) + (size_t)h * DH;
    const size_t tile0 = ((size_t)(((b * 2 + n) * 16 + h) * 32)) * 8192;

    // ---------------- Q fragments (RoPE'd via table, f16) ----------------
    f16x8  qf[2][4];
    float  mrun[2][4], lrun[2][4];
    f32x4  o[2][8];
    const f32x4 ZERO4 = {0.f, 0.f, 0.f, 0.f};

#pragma unroll
    for (int rs = 0; rs < 2; ++rs) {
#pragma unroll
        for (int r = 0; r < 4; ++r) { mrun[rs][r] = -NEGV; lrun[rs][r] = 0.f; }
#pragma unroll
        for (int dt = 0; dt < 8; ++dt) o[rs][dt] = ZERO4;

        const int tg = n * CHUNKL + q0 + w * 32 + rs * 16 + m;
        const float* qp = Q + bh + (size_t)tg * (HH * DH);
#pragma unroll
        for (int kc = 0; kc < 4; ++kc) {
            const int dbase = kc * 32 + g * 8;
            const int dlo   = dbase & 63;
            f32x4 xa0 = *(const f32x4*)(qp + dbase);
            f32x4 xa1 = *(const f32x4*)(qp + dbase + 4);
            f32x4 xb0 = *(const f32x4*)(qp + (dbase ^ 64));
            f32x4 xb1 = *(const f32x4*)(qp + (dbase ^ 64) + 4);
            float cc[8], ss[8];
            *(f32x4*)&cc[0] = *(const f32x4*)(tab + tg * 64 + dlo);
            *(f32x4*)&cc[4] = *(const f32x4*)(tab + tg * 64 + dlo + 4);
            *(f32x4*)&ss[0] = *(const f32x4*)(tab + T_TOT * 64 + tg * 64 + dlo);
            *(f32x4*)&ss[4] = *(const f32x4*)(tab + T_TOT * 64 + tg * 64 + dlo + 4);
            const float sgn = (dbase < 64) ? -1.f : 1.f;
            float xa[8] = {xa0[0],xa0[1],xa0[2],xa0[3],xa1[0],xa1[1],xa1[2],xa1[3]};
            float xb[8] = {xb0[0],xb0[1],xb0[2],xb0[3],xb1[0],xb1[1],xb1[2],xb1[3]};
            f16x8 f;
#pragma unroll
            for (int j = 0; j < 8; ++j) f[j] = (f16)(xa[j] * cc[j] + sgn * xb[j] * ss[j]);
            qf[rs][kc] = f;
        }
    }

    // ---------------- main K/V-tile loop ----------------
    const int nkt = 2 * qt + 2;
    for (int kt = 0; kt < nkt; ++kt) {
        __syncthreads();

        // ---- stage K & VT tiles: pure 16B global->LDS DMA, swizzle pre-baked ----
        const f16* ks = Kws  + tile0 + (size_t)kt * 8192;
        const f16* vs = VTws + tile0 + (size_t)kt * 8192;
#pragma unroll
        for (int i = 0; i < 4; ++i) {
            const int off = (i * 4 + w) * 512;           // f16 elements (1KB chunks)
            __builtin_amdgcn_global_load_lds(AS_G(ks + off + lane * 8), AS_L(&Kl[off]),  16, 0, 0);
            __builtin_amdgcn_global_load_lds(AS_G(vs + off + lane * 8), AS_L(&VTl[off]), 16, 0, 0);
        }
        __syncthreads();

        const bool active = (kt * KTILE) < (q0 + w * 32 + 32);
        if (active) {
            // ---- QK^T : S[32 q][64 k] per wave ----
            f32x4 sa[2][4];
#pragma unroll
            for (int rs = 0; rs < 2; ++rs)
#pragma unroll
                for (int nt = 0; nt < 4; ++nt) sa[rs][nt] = ZERO4;

#pragma unroll
            for (int nt = 0; nt < 4; ++nt) {
                const int key = nt * 16 + m;
                const int swk = (key & 7) << 3;
#pragma unroll
                for (int kc = 0; kc < 4; ++kc) {
                    f16x8 bf = *(const f16x8*)&Kl[key * DH + ((kc * 32 + g * 8) ^ swk)];
                    sa[0][nt] = mfma16(qf[0][kc], bf, sa[0][nt]);
                    sa[1][nt] = mfma16(qf[1][kc], bf, sa[1][nt]);
                }
            }

            // ---- online softmax ----
            const bool domask = (kt >= 2 * qt);
#pragma unroll
            for (int rs = 0; rs < 2; ++rs) {
                if (domask) {
#pragma unroll
                    for (int nt = 0; nt < 4; ++nt) {
                        const int key = kt * KTILE + nt * 16 + m;
#pragma unroll
                        for (int r = 0; r < 4; ++r) {
                            const int qr = q0 + w * 32 + rs * 16 + 4 * g + r;
                            if (key > qr) sa[rs][nt][r] = -NEGV;
                        }
                    }
                }
                float mx[4];
#pragma unroll
                for (int r = 0; r < 4; ++r)
                    mx[r] = fmaxf(fmaxf(sa[rs][0][r], sa[rs][1][r]),
                                  fmaxf(sa[rs][2][r], sa[rs][3][r]));
#pragma unroll
                for (int off = 1; off < 16; off <<= 1)
#pragma unroll
                    for (int r = 0; r < 4; ++r)
                        mx[r] = fmaxf(mx[r], __shfl_xor(mx[r], off));

                float al[4], ps[4];
#pragma unroll
                for (int r = 0; r < 4; ++r) {
                    const float mn = fmaxf(mrun[rs][r], mx[r]);
                    al[r] = exp2f((mrun[rs][r] - mn) * L2E);
                    mrun[rs][r] = mn;
                    ps[r] = 0.f;
                }
#pragma unroll
                for (int nt = 0; nt < 4; ++nt)
#pragma unroll
                    for (int r = 0; r < 4; ++r) {
                        const float p = exp2f((sa[rs][nt][r] - mrun[rs][r]) * L2E);
                        sa[rs][nt][r] = p;
                        ps[r] += p;
                    }
#pragma unroll
                for (int off = 1; off < 16; off <<= 1)
#pragma unroll
                    for (int r = 0; r < 4; ++r)
                        ps[r] += __shfl_xor(ps[r], off);
#pragma unroll
                for (int r = 0; r < 4; ++r)
                    lrun[rs][r] = lrun[rs][r] * al[r] + ps[r];
#pragma unroll
                for (int dt = 0; dt < 8; ++dt)
#pragma unroll
                    for (int r = 0; r < 4; ++r)
                        o[rs][dt][r] *= al[r];
#pragma unroll
                for (int nt = 0; nt < 4; ++nt)
#pragma unroll
                    for (int r = 0; r < 4; ++r)
                        Pl[w][(rs * 16 + 4 * g + r) * 72 + nt * 16 + m] = (f16)sa[rs][nt][r];
            }

            // ---- P A-fragments + PV ----
            f16x8 pa[2][2];
#pragma unroll
            for (int rs = 0; rs < 2; ++rs)
#pragma unroll
                for (int kc = 0; kc < 2; ++kc)
                    pa[rs][kc] = *(const f16x8*)&Pl[w][(rs * 16 + m) * 72 + kc * 32 + g * 8];

#pragma unroll
            for (int dt = 0; dt < 8; ++dt) {
                const int d   = dt * 16 + m;
                const int swv = (d & 7) << 3;
#pragma unroll
                for (int kc = 0; kc < 2; ++kc) {
                    f16x8 vf = *(const f16x8*)&VTl[d * KTILE + ((kc * 32 + g * 8) ^ swv)];
                    o[0][dt] = mfma16(pa[0][kc], vf, o[0][dt]);
                    o[1][dt] = mfma16(pa[1][kc], vf, o[1][dt]);
                }
            }
        }
    }

    // ---------------- epilogue ----------------
#pragma unroll
    for (int rs = 0; rs < 2; ++rs) {
#pragma unroll
        for (int r = 0; r < 4; ++r) {
            const float inv = 1.0f / lrun[rs][r];
            const int tg = n * CHUNKL + q0 + w * 32 + rs * 16 + 4 * g + r;
            float* op = O + bh + (size_t)tg * (HH * DH);
#pragma unroll
            for (int dt = 0; dt < 8; ++dt)
                op[dt * 16 + m] = o[rs][dt][r] * inv;
        }
    }
}

// ---------------------------------------------------------------------------
// Fallback (no/small ws): self-contained, RoPE inline. Same math as R2 kernel.
__global__ __launch_bounds__(THREADS, 2)
void attn_kernel(const float* __restrict__ Q, const float* __restrict__ K,
                 const float* __restrict__ V, const int* __restrict__ startp,
                 float* __restrict__ O)
{
    __shared__ f16 Kl[KTILE * DH];
    __shared__ f16 VTl[DH * KTILE];
    __shared__ f16 Pl[4][32 * 72];

    const int bid = blockIdx.x;
    const int qt  = 15 - (bid & 15);
    const int bnh = bid >> 4;
    const int h = bnh & 15, n = (bnh >> 4) & 1, b = bnh >> 5;

    const int tid  = threadIdx.x;
    const int w    = tid >> 6;
    const int lane = tid & 63;
    const int g    = lane >> 4, m = lane & 15;

    const int q0 = qt * QT;
    const size_t bh = (size_t)b * T_TOT * (HH * DH) + (size_t)h * DH;
    const int start = *startp;

    f16x8  qf[2][4];
    float  mrun[2][4], lrun[2][4];
    f32x4  o[2][8];
    const f32x4 ZERO4 = {0.f, 0.f, 0.f, 0.f};

#pragma unroll
    for (int rs = 0; rs < 2; ++rs) {
#pragma unroll
        for (int r = 0; r < 4; ++r) { mrun[rs][r] = -NEGV; lrun[rs][r] = 0.f; }
#pragma unroll
        for (int dt = 0; dt < 8; ++dt) o[rs][dt] = ZERO4;

        const int tg = n * CHUNKL + q0 + w * 32 + rs * 16 + m;
        const float* qp = Q + bh + (size_t)tg * (HH * DH);
#pragma unroll
        for (int kc = 0; kc < 4; ++kc) {
            const int dbase = kc * 32 + g * 8;
            const int dlo   = dbase & 63;
            f32x4 xa0 = *(const f32x4*)(qp + dbase);
            f32x4 xa1 = *(const f32x4*)(qp + dbase + 4);
            f32x4 xb0 = *(const f32x4*)(qp + (dbase ^ 64));
            f32x4 xb1 = *(const f32x4*)(qp + (dbase ^ 64) + 4);
            float cc[8], ss[8];
#pragma unroll
            for (int j = 0; j < 8; ++j) {
                float invf = expf((float)(dlo + j) * (-9.210340371976184f / 64.0f));
                sincosf((float)(tg + start) * invf, &ss[j], &cc[j]);
            }
            const float sgn = (dbase < 64) ? -1.f : 1.f;
            float xa[8] = {xa0[0],xa0[1],xa0[2],xa0[3],xa1[0],xa1[1],xa1[2],xa1[3]};
            float xb[8] = {xb0[0],xb0[1],xb0[2],xb0[3],xb1[0],xb1[1],xb1[2],xb1[3]};
            f16x8 f;
#pragma unroll
            for (int j = 0; j < 8; ++j) f[j] = (f16)(xa[j] * cc[j] + sgn * xb[j] * ss[j]);
            qf[rs][kc] = f;
        }
    }

    const int nkt = 2 * qt + 2;
    for (int kt = 0; kt < nkt; ++kt) {
        __syncthreads();
#pragma unroll
        for (int it = 0; it < 4; ++it) {
            const int tau = tid + THREADS * it;
            const int row = tau >> 4;
            const int d0  = (tau & 15) << 2;
            const int tg  = n * CHUNKL + kt * KTILE + row;
            const float* kp = K + bh + (size_t)tg * (HH * DH);
            f32x4 xa = *(const f32x4*)(kp + d0);
            f32x4 xb = *(const f32x4*)(kp + d0 + 64);
            f32x4 cc, ss;
#pragma unroll
            for (int j = 0; j < 4; ++j) {
                float invf = expf((float)(d0 + j) * (-9.210340371976184f / 64.0f));
                float sv, cv;
                sincosf((float)(tg + start) * invf, &sv, &cv);
                cc[j] = cv; ss[j] = sv;
            }
            f16x4 oA, oB;
#pragma unroll
            for (int j = 0; j < 4; ++j) {
                oA[j] = (f16)(xa[j] * cc[j] - xb[j] * ss[j]);
                oB[j] = (f16)(xb[j] * cc[j] + xa[j] * ss[j]);
            }
            const int sw = (row & 7) << 3;
            *(f16x4*)&Kl[row * DH + (d0 ^ sw)]        = oA;
            *(f16x4*)&Kl[row * DH + ((d0 + 64) ^ sw)] = oB;
        }
#pragma unroll
        for (int it = 0; it < 8; ++it) {
            const int tau = tid + THREADS * it;
            const int key = tau & 63;
            const int d0  = (tau >> 6) << 2;
            const int tg  = n * CHUNKL + kt * KTILE + key;
            f32x4 x = *(const f32x4*)(V + bh + (size_t)tg * (HH * DH) + d0);
#pragma unroll
            for (int j = 0; j < 4; ++j) {
                const int d = d0 + j;
                VTl[d * KTILE + (key ^ ((d & 7) << 3))] = (f16)x[j];
            }
        }
        __syncthreads();

        const bool active = (kt * KTILE) < (q0 + w * 32 + 32);
        if (active) {
            f32x4 sa[2][4];
#pragma unroll
            for (int rs = 0; rs < 2; ++rs)
#pragma unroll
                for (int nt = 0; nt < 4; ++nt) sa[rs][nt] = ZERO4;
#pragma unroll
            for (int nt = 0; nt < 4; ++nt) {
                const int key = nt * 16 + m;
                const int swk = (key & 7) << 3;
#pragma unroll
                for (int kc = 0; kc < 4; ++kc) {
                    f16x8 bf = *(const f16x8*)&Kl[key * DH + ((kc * 32 + g * 8) ^ swk)];
                    sa[0][nt] = mfma16(qf[0][kc], bf, sa[0][nt]);
                    sa[1][nt] = mfma16(qf[1][kc], bf, sa[1][nt]);
                }
            }
            const bool domask = (kt >= 2 * qt);
#pragma unroll
            for (int rs = 0; rs < 2; ++rs) {
                if (domask) {
#pragma unroll
                    for (int nt = 0; nt < 4; ++nt) {
                        const int key = kt * KTILE + nt * 16 + m;
#pragma unroll
                        for (int r = 0; r < 4; ++r) {
                            const int qr = q0 + w * 32 + rs * 16 + 4 * g + r;
                            if (key > qr) sa[rs][nt][r] = -NEGV;
                        }
                    }
                }
                float mx[4];
#pragma unroll
                for (int r = 0; r < 4; ++r)
                    mx[r] = fmaxf(fmaxf(sa[rs][0][r], sa[rs][1][r]),
                                  fmaxf(sa[rs][2][r], sa[rs][3][r]));
#pragma unroll
                for (int off = 1; off < 16; off <<= 1)
#pragma unroll
                    for (int r = 0; r < 4; ++r)
                        mx[r] = fmaxf(mx[r], __shfl_xor(mx[r], off));
                float al[4], ps[4];
#pragma unroll
                for (int r = 0; r < 4; ++r) {
                    const float mn = fmaxf(mrun[rs][r], mx[r]);
                    al[r] = exp2f((mrun[rs][r] - mn) * L2E);
                    mrun[rs][r] = mn;
                    ps[r] = 0.f;
                }
#pragma unroll
                for (int nt = 0; nt < 4; ++nt)
#pragma unroll
                    for (int r = 0; r < 4; ++r) {
                        const float p = exp2f((sa[rs][nt][r] - mrun[rs][r]) * L2E);
                        sa[rs][nt][r] = p;
                        ps[r] += p;
                    }
#pragma unroll
                for (int off = 1; off < 16; off <<= 1)
#pragma unroll
                    for (int r = 0; r < 4; ++r)
                        ps[r] += __shfl_xor(ps[r], off);
#pragma unroll
                for (int r = 0; r < 4; ++r)
                    lrun[rs][r] = lrun[rs][r] * al[r] + ps[r];
#pragma unroll
                for (int dt = 0; dt < 8; ++dt)
#pragma unroll
                    for (int r = 0; r < 4; ++r)
                        o[rs][dt][r] *= al[r];
#pragma unroll
                for (int nt = 0; nt < 4; ++nt)
#pragma unroll
                    for (int r = 0; r < 4; ++r)
                        Pl[w][(rs * 16 + 4 * g + r) * 72 + nt * 16 + m] = (f16)sa[rs][nt][r];
            }
            f16x8 pa[2][2];
#pragma unroll
            for (int rs = 0; rs < 2; ++rs)
#pragma unroll
                for (int kc = 0; kc < 2; ++kc)
                    pa[rs][kc] = *(const f16x8*)&Pl[w][(rs * 16 + m) * 72 + kc * 32 + g * 8];
#pragma unroll
            for (int dt = 0; dt < 8; ++dt) {
                const int d   = dt * 16 + m;
                const int swv = (d & 7) << 3;
#pragma unroll
                for (int kc = 0; kc < 2; ++kc) {
                    f16x8 vf = *(const f16x8*)&VTl[d * KTILE + ((kc * 32 + g * 8) ^ swv)];
                    o[0][dt] = mfma16(pa[0][kc], vf, o[0][dt]);
                    o[1][dt] = mfma16(pa[1][kc], vf, o[1][dt]);
                }
            }
        }
    }

#pragma unroll
    for (int rs = 0; rs < 2; ++rs) {
#pragma unroll
        for (int r = 0; r < 4; ++r) {
            const float inv = 1.0f / lrun[rs][r];
            const int tg = n * CHUNKL + q0 + w * 32 + rs * 16 + 4 * g + r;
            float* op = O + bh + (size_t)tg * (HH * DH);
#pragma unroll
            for (int dt = 0; dt < 8; ++dt)
                op[dt * 16 + m] = o[rs][dt][r] * inv;
        }
    }
}

extern "C" void kernel_launch(void* const* d_in, const int* in_sizes, int n_in,
                              void* d_out, int out_size, void* d_ws, size_t ws_size,
                              hipStream_t stream) {
    const float* q = (const float*)d_in[0];
    const float* k = (const float*)d_in[1];
    const float* v = (const float*)d_in[2];
    const int* start = (const int*)d_in[3];
    float* out = (float*)d_out;

    const size_t tab_elems = (size_t)2 * T_TOT * 64;               // 512K floats, 2MB
    const size_t kv_elems  = (size_t)2 * T_TOT * HH * DH;          // 16.7M f16, 32MB each
    const size_t need = tab_elems * sizeof(float) + 2 * kv_elems * sizeof(f16); // 66MB
    const int nblocks = 64 * 16;

    if (ws_size >= need) {
        float* tab = (float*)d_ws;
        f16* Kws  = (f16*)((char*)d_ws + tab_elems * sizeof(float));
        f16* VTws = Kws + kv_elems;
        rope_table_kernel<<<(T_TOT * 64) / THREADS, THREADS, 0, stream>>>(tab, start);
        prep_k_kernel<<<(int)(kv_elems / 8 / THREADS), THREADS, 0, stream>>>(k, tab, Kws);
        prep_v_kernel<<<(int)(kv_elems / 4 / THREADS), THREADS, 0, stream>>>(v, VTws);
        attn_fast_kernel<<<nblocks, THREADS, 0, stream>>>(q, Kws, VTws, tab, out);
    } else {
        attn_kernel<<<nblocks, THREADS, 0, stream>>>(q, k, v, start, out);
    }
}